// Round 2
// baseline (5513.693 us; speedup 1.0000x reference)
//
#include <hip/hip_runtime.h>
#include <hip/hip_bf16.h>

#define BB 4
#define TT 2048
#define DD 1024
#define HH 2048
#define NE (BB * TT * DD)   /* 8388608 */
#define BT (BB * TT)        /* 8192 */

static __device__ __forceinline__ float wave_reduce_sum(float v) {
#pragma unroll
  for (int off = 32; off > 0; off >>= 1) v += __shfl_xor(v, off);
  return v;
}

// ---------------- RMSNorm: one wave per row (1024 cols, 16 f/lane) ----------
__global__ __launch_bounds__(256) void rmsnorm_kernel(
    const float* __restrict__ x, const float* __restrict__ w,
    float* __restrict__ out) {
  int row = blockIdx.x * 4 + (threadIdx.x >> 6);
  int lane = threadIdx.x & 63;
  const float4* xr = (const float4*)(x + (size_t)row * DD);
  const float4* wr = (const float4*)w;
  float4 v[4];
  float ss = 0.f;
#pragma unroll
  for (int e = 0; e < 4; e++) {
    v[e] = xr[lane + 64 * e];
    ss += v[e].x * v[e].x + v[e].y * v[e].y + v[e].z * v[e].z + v[e].w * v[e].w;
  }
  ss = wave_reduce_sum(ss);
  float r = rsqrtf(ss * (1.f / DD) + 1e-6f);
  float4* orow = (float4*)(out + (size_t)row * DD);
#pragma unroll
  for (int e = 0; e < 4; e++) {
    float4 wv = wr[lane + 64 * e];
    float4 ov;
    ov.x = v[e].x * r * wv.x; ov.y = v[e].y * r * wv.y;
    ov.z = v[e].z * r * wv.z; ov.w = v[e].w * r * wv.w;
    orow[lane + 64 * e] = ov;
  }
}

// ---------------- k row L2-normalize (in place) ------------------------------
__global__ __launch_bounds__(256) void knorm_kernel(float* __restrict__ k) {
  int row = blockIdx.x * 4 + (threadIdx.x >> 6);
  int lane = threadIdx.x & 63;
  float4* kr = (float4*)(k + (size_t)row * DD);
  float4 v[4];
  float ss = 0.f;
#pragma unroll
  for (int e = 0; e < 4; e++) {
    v[e] = kr[lane + 64 * e];
    ss += v[e].x * v[e].x + v[e].y * v[e].y + v[e].z * v[e].z + v[e].w * v[e].w;
  }
  ss = wave_reduce_sum(ss);
  float r = 1.f / fmaxf(sqrtf(ss), 1e-12f);
#pragma unroll
  for (int e = 0; e < 4; e++) {
    float4 ov;
    ov.x = v[e].x * r; ov.y = v[e].y * r; ov.z = v[e].z * r; ov.w = v[e].w * r;
    kr[lane + 64 * e] = ov;
  }
}

// ---------------- beta = sigmoid(h . beta_w + beta_b), one wave per row ------
__global__ __launch_bounds__(256) void beta_kernel(
    const float* __restrict__ h, const float* __restrict__ bw,
    const float* __restrict__ bbias, float* __restrict__ beta) {
  int row = blockIdx.x * 4 + (threadIdx.x >> 6);
  int lane = threadIdx.x & 63;
  const float4* hr = (const float4*)(h + (size_t)row * DD);
  const float4* wr = (const float4*)bw;
  float p = 0.f;
#pragma unroll
  for (int e = 0; e < 4; e++) {
    float4 a = hr[lane + 64 * e];
    float4 b = wr[lane + 64 * e];
    p += a.x * b.x + a.y * b.y + a.z * b.z + a.w * b.w;
  }
  p = wave_reduce_sum(p);
  if (lane == 0) beta[row] = 1.f / (1.f + expf(-(p + bbias[0])));
}

// ---------------- EMA over T, one thread per (b,d) chain, in place -----------
__global__ __launch_bounds__(256) void ema_kernel(
    float* __restrict__ v, const float* __restrict__ alpha_logit) {
  int idx = blockIdx.x * 256 + threadIdx.x;  // 0..4095
  int b = idx >> 10, d = idx & (DD - 1);
  float a = 1.f / (1.f + expf(-alpha_logit[d]));
  float om = 1.f - a;
  float* p = v + (size_t)b * TT * DD + d;
  float s = 0.f;
  for (int t = 0; t < TT; t += 8) {
    float vt[8];
#pragma unroll
    for (int u = 0; u < 8; u++) vt[u] = p[(size_t)(t + u) * DD];
#pragma unroll
    for (int u = 0; u < 8; u++) {
      s = a * vt[u] + om * s;
      p[(size_t)(t + u) * DD] = s;
    }
  }
}

// ---------------- delta-rule scan -------------------------------------------
// 512 blocks x 256 thr. Block = (batch, 8 rows). Wave = 2 rows, state in VGPRs
// (16 cols/lane, col j = lane + 64u). k_t/q_t double-buffered in LDS.
__global__ __launch_bounds__(256) void delta_scan_kernel(
    const float* __restrict__ q, const float* __restrict__ k,
    const float* __restrict__ v, const float* __restrict__ beta,
    float* __restrict__ o) {
  __shared__ float kb[2][DD];
  __shared__ float qb[2][DD];
  __shared__ float vb[2][8];
  __shared__ float bb_s[2];
  int wg = blockIdx.x;
  int b = wg >> 7;
  int rb = (wg & 127) * 8;
  int tid = threadIdx.x;
  int wv = tid >> 6, lane = tid & 63;
  int r0 = rb + wv * 2;
  float s0[16], s1[16];
#pragma unroll
  for (int u = 0; u < 16; u++) { s0[u] = 0.f; s1[u] = 0.f; }
  const size_t base = (size_t)b * TT * DD;
  // preload t=0
  ((float4*)kb[0])[tid] = ((const float4*)(k + base))[tid];
  ((float4*)qb[0])[tid] = ((const float4*)(q + base))[tid];
  if (tid < 8) vb[0][tid] = v[base + rb + tid];
  if (tid == 8) bb_s[0] = beta[b * TT];

  for (int t = 0; t < TT; t++) {
    int buf = t & 1;
    __syncthreads();
    if (t + 1 < TT) {  // prefetch t+1 into the other buffer
      size_t off = base + (size_t)(t + 1) * DD;
      ((float4*)kb[buf ^ 1])[tid] = ((const float4*)(k + off))[tid];
      ((float4*)qb[buf ^ 1])[tid] = ((const float4*)(q + off))[tid];
      if (tid < 8) vb[buf ^ 1][tid] = v[off + rb + tid];
      if (tid == 8) bb_s[buf ^ 1] = beta[b * TT + t + 1];
    }
    float kk[16], qq[16];
#pragma unroll
    for (int u = 0; u < 16; u++) {
      kk[u] = kb[buf][lane + 64 * u];
      qq[u] = qb[buf][lane + 64 * u];
    }
    float pa0 = 0.f, pa1 = 0.f;
#pragma unroll
    for (int u = 0; u < 16; u++) {
      pa0 = fmaf(s0[u], kk[u], pa0);
      pa1 = fmaf(s1[u], kk[u], pa1);
    }
#pragma unroll
    for (int off = 32; off > 0; off >>= 1) {
      pa0 += __shfl_xor(pa0, off);
      pa1 += __shfl_xor(pa1, off);
    }
    float bt = bb_s[buf];
    float c0 = bt * (vb[buf][wv * 2] - pa0);
    float c1 = bt * (vb[buf][wv * 2 + 1] - pa1);
    float pq0 = 0.f, pq1 = 0.f;
#pragma unroll
    for (int u = 0; u < 16; u++) {
      s0[u] = fmaf(c0, kk[u], s0[u]);
      s1[u] = fmaf(c1, kk[u], s1[u]);
      pq0 = fmaf(s0[u], qq[u], pq0);
      pq1 = fmaf(s1[u], qq[u], pq1);
    }
#pragma unroll
    for (int off = 32; off > 0; off >>= 1) {
      pq0 += __shfl_xor(pq0, off);
      pq1 += __shfl_xor(pq1, off);
    }
    if (lane == 0) {
      float2 st; st.x = pq0; st.y = pq1;
      *(float2*)(o + base + (size_t)t * DD + r0) = st;
    }
  }
}

// ---------------- fp32 tiled GEMM: C = A@B (+R) [MODE 0/1] ------------------
// MODE 0: C = A@B. MODE 1: C = A@B + R. (all fp32)
template <int MODE>
__global__ __launch_bounds__(256) void gemm_kernel(
    const float* __restrict__ A, const float* __restrict__ Bm,
    const float* __restrict__ R, float* __restrict__ C,
    int M, int N, int K) {
  __shared__ float As[16][68];
  __shared__ float Bs[16][64];
  int tid = threadIdx.x;
  int tx = tid & 15, ty = tid >> 4;
  int arow = tid >> 2, ac4 = tid & 3;
  int brow = tid >> 4, bc4 = tid & 15;
  int bx = blockIdx.x, by = blockIdx.y;
  float c[4][4] = {};
  const float* Ap = A + (size_t)(by * 64 + arow) * K + ac4 * 4;
  const float* Bp = Bm + (size_t)brow * N + bx * 64 + bc4 * 4;
  for (int k0 = 0; k0 < K; k0 += 16) {
    float4 a4 = *(const float4*)(Ap + k0);
    float4 b4 = *(const float4*)(Bp + (size_t)k0 * N);
    As[ac4 * 4 + 0][arow] = a4.x;
    As[ac4 * 4 + 1][arow] = a4.y;
    As[ac4 * 4 + 2][arow] = a4.z;
    As[ac4 * 4 + 3][arow] = a4.w;
    *(float4*)&Bs[brow][bc4 * 4] = b4;
    __syncthreads();
#pragma unroll
    for (int kk = 0; kk < 16; kk++) {
      float4 av = *(const float4*)&As[kk][ty * 4];
      float4 bv = *(const float4*)&Bs[kk][tx * 4];
      float aa[4] = {av.x, av.y, av.z, av.w};
      float bb_[4] = {bv.x, bv.y, bv.z, bv.w};
#pragma unroll
      for (int i = 0; i < 4; i++)
#pragma unroll
        for (int j = 0; j < 4; j++) c[i][j] = fmaf(aa[i], bb_[j], c[i][j]);
    }
    __syncthreads();
  }
  int crow0 = by * 64 + ty * 4;
  int ccol0 = bx * 64 + tx * 4;
#pragma unroll
  for (int i = 0; i < 4; i++) {
    size_t off = (size_t)(crow0 + i) * N + ccol0;
    if constexpr (MODE == 0) {
      float4 st; st.x = c[i][0]; st.y = c[i][1]; st.z = c[i][2]; st.w = c[i][3];
      *(float4*)(C + off) = st;
    } else {
      float4 rr = *(const float4*)(R + off);
      float4 st;
      st.x = c[i][0] + rr.x; st.y = c[i][1] + rr.y;
      st.z = c[i][2] + rr.z; st.w = c[i][3] + rr.w;
      *(float4*)(C + off) = st;
    }
  }
}

// ---------------- fused gate/up GEMM: act = silu(A@Bg) * (A@Bu) --------------
__global__ __launch_bounds__(256) void gemm_gateup_kernel(
    const float* __restrict__ A, const float* __restrict__ Bg,
    const float* __restrict__ Bu, float* __restrict__ act,
    int M, int N, int K) {
  __shared__ float As[16][68];
  __shared__ float Bgs[16][64];
  __shared__ float Bus[16][64];
  int tid = threadIdx.x;
  int tx = tid & 15, ty = tid >> 4;
  int arow = tid >> 2, ac4 = tid & 3;
  int brow = tid >> 4, bc4 = tid & 15;
  int bx = blockIdx.x, by = blockIdx.y;
  float cg[4][4] = {}, cu[4][4] = {};
  const float* Ap = A + (size_t)(by * 64 + arow) * K + ac4 * 4;
  const float* Bgp = Bg + (size_t)brow * N + bx * 64 + bc4 * 4;
  const float* Bup = Bu + (size_t)brow * N + bx * 64 + bc4 * 4;
  for (int k0 = 0; k0 < K; k0 += 16) {
    float4 a4 = *(const float4*)(Ap + k0);
    float4 g4 = *(const float4*)(Bgp + (size_t)k0 * N);
    float4 u4 = *(const float4*)(Bup + (size_t)k0 * N);
    As[ac4 * 4 + 0][arow] = a4.x;
    As[ac4 * 4 + 1][arow] = a4.y;
    As[ac4 * 4 + 2][arow] = a4.z;
    As[ac4 * 4 + 3][arow] = a4.w;
    *(float4*)&Bgs[brow][bc4 * 4] = g4;
    *(float4*)&Bus[brow][bc4 * 4] = u4;
    __syncthreads();
#pragma unroll
    for (int kk = 0; kk < 16; kk++) {
      float4 av = *(const float4*)&As[kk][ty * 4];
      float4 gv = *(const float4*)&Bgs[kk][tx * 4];
      float4 uv = *(const float4*)&Bus[kk][tx * 4];
      float aa[4] = {av.x, av.y, av.z, av.w};
      float gg[4] = {gv.x, gv.y, gv.z, gv.w};
      float uu[4] = {uv.x, uv.y, uv.z, uv.w};
#pragma unroll
      for (int i = 0; i < 4; i++)
#pragma unroll
        for (int j = 0; j < 4; j++) {
          cg[i][j] = fmaf(aa[i], gg[j], cg[i][j]);
          cu[i][j] = fmaf(aa[i], uu[j], cu[i][j]);
        }
    }
    __syncthreads();
  }
  int crow0 = by * 64 + ty * 4;
  int ccol0 = bx * 64 + tx * 4;
#pragma unroll
  for (int i = 0; i < 4; i++) {
    size_t off = (size_t)(crow0 + i) * N + ccol0;
    float4 st;
    float g0 = cg[i][0], g1 = cg[i][1], g2 = cg[i][2], g3 = cg[i][3];
    st.x = (g0 / (1.f + expf(-g0))) * cu[i][0];
    st.y = (g1 / (1.f + expf(-g1))) * cu[i][1];
    st.z = (g2 / (1.f + expf(-g2))) * cu[i][2];
    st.w = (g3 / (1.f + expf(-g3))) * cu[i][3];
    *(float4*)(act + off) = st;
  }
}

// ---------------- launch -----------------------------------------------------
extern "C" void kernel_launch(void* const* d_in, const int* in_sizes, int n_in,
                              void* d_out, int out_size, void* d_ws,
                              size_t ws_size, hipStream_t stream) {
  const float* x   = (const float*)d_in[0];
  const float* n1w = (const float*)d_in[1];
  const float* Wq  = (const float*)d_in[2];
  const float* Wk  = (const float*)d_in[3];
  const float* Wv  = (const float*)d_in[4];
  const float* bw  = (const float*)d_in[5];
  const float* bbp = (const float*)d_in[6];
  const float* Wo  = (const float*)d_in[7];
  const float* al  = (const float*)d_in[8];
  const float* n2w = (const float*)d_in[9];
  const float* Wg  = (const float*)d_in[10];
  const float* Wu  = (const float*)d_in[11];
  const float* Wd  = (const float*)d_in[12];
  float* out = (float*)d_out;  // reference output dtype is float32
  float* ws = (float*)d_ws;

  // workspace layout (floats), with aliasing per liveness:
  float* h    = ws;                    // [0, NE)
  float* q    = ws + (size_t)NE;       // [NE, 2NE)
  float* k    = ws + 2 * (size_t)NE;   // [2NE, 3NE)
  float* v    = ws + 3 * (size_t)NE;   // [3NE, 4NE)
  float* o    = ws;                    // alias h (dead after beta)
  float* act  = ws + 2 * (size_t)NE;   // alias k+v (dead after scan), 2*NE = BT*HH
  float* x1   = ws + 4 * (size_t)NE;   // [4NE, 5NE)
  float* h2   = ws + (size_t)NE;       // alias q (dead after scan)
  float* beta = ws + 5 * (size_t)NE;   // [5NE, 5NE+BT)

  rmsnorm_kernel<<<BT / 4, 256, 0, stream>>>(x, n1w, h);

  dim3 g1(DD / 64, BT / 64);  // (16,128)
  gemm_kernel<0><<<g1, 256, 0, stream>>>(h, Wq, nullptr, q, BT, DD, DD);
  gemm_kernel<0><<<g1, 256, 0, stream>>>(h, Wk, nullptr, k, BT, DD, DD);
  gemm_kernel<0><<<g1, 256, 0, stream>>>(h, Wv, nullptr, v, BT, DD, DD);
  beta_kernel<<<BT / 4, 256, 0, stream>>>(h, bw, bbp, beta);
  knorm_kernel<<<BT / 4, 256, 0, stream>>>(k);
  ema_kernel<<<(BB * DD) / 256, 256, 0, stream>>>(v, al);

  delta_scan_kernel<<<512, 256, 0, stream>>>(q, k, v, beta, o);

  gemm_kernel<1><<<g1, 256, 0, stream>>>(o, Wo, x, x1, BT, DD, DD);
  rmsnorm_kernel<<<BT / 4, 256, 0, stream>>>(x1, n2w, h2);

  dim3 g2(HH / 64, BT / 64);  // (32,128)
  gemm_gateup_kernel<<<g2, 256, 0, stream>>>(h2, Wg, Wu, act, BT, HH, DD);
  gemm_kernel<1><<<g1, 256, 0, stream>>>(act, Wd, x1, out, BT, DD, HH);
}

// Round 3
// 3388.871 us; speedup vs baseline: 1.6270x; 1.6270x over previous
//
#include <hip/hip_runtime.h>
#include <hip/hip_bf16.h>

#define BB 4
#define TT 2048
#define DD 1024
#define HH 2048
#define NE (BB * TT * DD)   /* 8388608 */
#define BT (BB * TT)        /* 8192 */

typedef unsigned int u32;
typedef unsigned short u16;
typedef __attribute__((ext_vector_type(8))) short bf16x8;
typedef __attribute__((ext_vector_type(4))) float f32x4;

static __device__ __forceinline__ u16 f2bf(float f) {
  u32 u = __float_as_uint(f);
  u32 r = (u + 0x7fffu + ((u >> 16) & 1u)) >> 16;  // RNE
  return (u16)r;
}

static __device__ __forceinline__ float wave_reduce_sum(float v) {
#pragma unroll
  for (int off = 32; off > 0; off >>= 1) v += __shfl_xor(v, off);
  return v;
}

// ---------- RMSNorm -> bf16 out; optionally fused beta = sigmoid(h.bw+b) ----
template <int WITH_BETA>
__global__ __launch_bounds__(256) void rmsnorm_bf16_kernel(
    const float* __restrict__ x, const float* __restrict__ w,
    const float* __restrict__ bw, const float* __restrict__ bbias,
    u32* __restrict__ hb, float* __restrict__ beta) {
  int row = blockIdx.x * 4 + (threadIdx.x >> 6);
  int lane = threadIdx.x & 63;
  const float4* xr = (const float4*)(x + (size_t)row * DD);
  const float4* wr = (const float4*)w;
  float4 v[4];
  float ss = 0.f;
#pragma unroll
  for (int e = 0; e < 4; e++) {
    v[e] = xr[lane + 64 * e];
    ss += v[e].x * v[e].x + v[e].y * v[e].y + v[e].z * v[e].z + v[e].w * v[e].w;
  }
  ss = wave_reduce_sum(ss);
  float r = rsqrtf(ss * (1.f / DD) + 1e-6f);
  u32* orow = hb + (size_t)row * (DD / 2);
  float p = 0.f;
#pragma unroll
  for (int e = 0; e < 4; e++) {
    float4 wv = wr[lane + 64 * e];
    float hx = v[e].x * r * wv.x, hy = v[e].y * r * wv.y;
    float hz = v[e].z * r * wv.z, hw = v[e].w * r * wv.w;
    uint2 pk;
    pk.x = (u32)f2bf(hx) | ((u32)f2bf(hy) << 16);
    pk.y = (u32)f2bf(hz) | ((u32)f2bf(hw) << 16);
    *(uint2*)(orow + (lane + 64 * e) * 2) = pk;
    if (WITH_BETA) {
      float4 bv = ((const float4*)bw)[lane + 64 * e];
      p += hx * bv.x + hy * bv.y + hz * bv.z + hw * bv.w;
    }
  }
  if (WITH_BETA) {
    p = wave_reduce_sum(p);
    if (lane == 0) beta[row] = 1.f / (1.f + expf(-(p + bbias[0])));
  }
}

// ---------- k row L2-normalize (in place, fp32) ------------------------------
__global__ __launch_bounds__(256) void knorm_kernel(float* __restrict__ k) {
  int row = blockIdx.x * 4 + (threadIdx.x >> 6);
  int lane = threadIdx.x & 63;
  float4* kr = (float4*)(k + (size_t)row * DD);
  float4 v[4];
  float ss = 0.f;
#pragma unroll
  for (int e = 0; e < 4; e++) {
    v[e] = kr[lane + 64 * e];
    ss += v[e].x * v[e].x + v[e].y * v[e].y + v[e].z * v[e].z + v[e].w * v[e].w;
  }
  ss = wave_reduce_sum(ss);
  float r = 1.f / fmaxf(sqrtf(ss), 1e-12f);
#pragma unroll
  for (int e = 0; e < 4; e++) {
    float4 ov;
    ov.x = v[e].x * r; ov.y = v[e].y * r; ov.z = v[e].z * r; ov.w = v[e].w * r;
    kr[lane + 64 * e] = ov;
  }
}

// ---------- EMA over T, one thread per (b,d) chain, in place -----------------
__global__ __launch_bounds__(256) void ema_kernel(
    float* __restrict__ v, const float* __restrict__ alpha_logit) {
  int idx = blockIdx.x * 256 + threadIdx.x;  // 0..4095
  int b = idx >> 10, d = idx & (DD - 1);
  float a = 1.f / (1.f + expf(-alpha_logit[d]));
  float om = 1.f - a;
  float* p = v + (size_t)b * TT * DD + d;
  float s = 0.f;
  for (int t = 0; t < TT; t += 8) {
    float vt[8];
#pragma unroll
    for (int u = 0; u < 8; u++) vt[u] = p[(size_t)(t + u) * DD];
#pragma unroll
    for (int u = 0; u < 8; u++) {
      s = a * vt[u] + om * s;
      p[(size_t)(t + u) * DD] = s;
    }
  }
}

// ---------- delta-rule scan: 5-dot single pass, bf16 out ---------------------
// o = S_new q = S_old q + c*(k.q); all dots (s.k, s.q per row + shared k.q)
// computed in one pass -> one reduce stage per step instead of two.
__global__ __launch_bounds__(256) void delta_scan_kernel(
    const float* __restrict__ q, const float* __restrict__ k,
    const float* __restrict__ v, const float* __restrict__ beta,
    u32* __restrict__ ob) {
  __shared__ float kb[2][DD];
  __shared__ float qb[2][DD];
  __shared__ float vb[2][8];
  __shared__ float bb_s[2];
  int wg = blockIdx.x;
  int b = wg >> 7;
  int rb = (wg & 127) * 8;
  int tid = threadIdx.x;
  int wv = tid >> 6, lane = tid & 63;
  int r0 = rb + wv * 2;
  float s0[16], s1[16];
#pragma unroll
  for (int u = 0; u < 16; u++) { s0[u] = 0.f; s1[u] = 0.f; }
  const size_t base = (size_t)b * TT * DD;
  const size_t base2 = base >> 1;
  ((float4*)kb[0])[tid] = ((const float4*)(k + base))[tid];
  ((float4*)qb[0])[tid] = ((const float4*)(q + base))[tid];
  if (tid < 8) vb[0][tid] = v[base + rb + tid];
  if (tid == 8) bb_s[0] = beta[b * TT];

  for (int t = 0; t < TT; t++) {
    int buf = t & 1;
    __syncthreads();
    if (t + 1 < TT) {
      size_t off = base + (size_t)(t + 1) * DD;
      ((float4*)kb[buf ^ 1])[tid] = ((const float4*)(k + off))[tid];
      ((float4*)qb[buf ^ 1])[tid] = ((const float4*)(q + off))[tid];
      if (tid < 8) vb[buf ^ 1][tid] = v[off + rb + tid];
      if (tid == 8) bb_s[buf ^ 1] = beta[b * TT + t + 1];
    }
    float kk[16], qq[16];
#pragma unroll
    for (int u = 0; u < 16; u++) {
      kk[u] = kb[buf][lane + 64 * u];
      qq[u] = qb[buf][lane + 64 * u];
    }
    float pa0 = 0.f, pa1 = 0.f, pq0 = 0.f, pq1 = 0.f, kq = 0.f;
#pragma unroll
    for (int u = 0; u < 16; u++) {
      pa0 = fmaf(s0[u], kk[u], pa0);
      pa1 = fmaf(s1[u], kk[u], pa1);
      pq0 = fmaf(s0[u], qq[u], pq0);
      pq1 = fmaf(s1[u], qq[u], pq1);
      kq  = fmaf(kk[u], qq[u], kq);
    }
#pragma unroll
    for (int off = 32; off > 0; off >>= 1) {
      pa0 += __shfl_xor(pa0, off);
      pa1 += __shfl_xor(pa1, off);
      pq0 += __shfl_xor(pq0, off);
      pq1 += __shfl_xor(pq1, off);
      kq  += __shfl_xor(kq, off);
    }
    float bt = bb_s[buf];
    float c0 = bt * (vb[buf][wv * 2] - pa0);
    float c1 = bt * (vb[buf][wv * 2 + 1] - pa1);
#pragma unroll
    for (int u = 0; u < 16; u++) {
      s0[u] = fmaf(c0, kk[u], s0[u]);
      s1[u] = fmaf(c1, kk[u], s1[u]);
    }
    if (lane == 0) {
      float o0 = pq0 + c0 * kq;
      float o1 = pq1 + c1 * kq;
      ob[base2 + (size_t)t * (DD / 2) + (r0 >> 1)] =
          (u32)f2bf(o0) | ((u32)f2bf(o1) << 16);
    }
  }
}

// ---------- transpose + fp32->bf16 weight convert: Wt[n][k] = W[k][n] --------
__global__ void transcvt_kernel(const float* __restrict__ W,
                                u16* __restrict__ Wt, int K, int N) {
  __shared__ float tile[32][33];
  int tx = threadIdx.x, ty = threadIdx.y;  // (32,8)
  int n0 = blockIdx.x * 32, k0 = blockIdx.y * 32;
#pragma unroll
  for (int i = 0; i < 4; i++)
    tile[ty + i * 8][tx] = W[(size_t)(k0 + ty + i * 8) * N + n0 + tx];
  __syncthreads();
#pragma unroll
  for (int i = 0; i < 4; i++)
    Wt[(size_t)(n0 + ty + i * 8) * K + k0 + tx] = f2bf(tile[tx][ty + i * 8]);
}

// ---------- bf16 MFMA GEMM: C(M,N) fp32 = A(M,K)bf16 @ Bt(N,K)bf16 (+R) ------
// 128x128 tile, BK=64, 4 waves 2x2, wave-tile 64x64 (4x4 frags of 16x16x32).
template <int ADD_R>
__global__ __launch_bounds__(256) void mgemm_kernel(
    const u16* __restrict__ A, const u16* __restrict__ Bt,
    const float* __restrict__ R, float* __restrict__ C,
    int M, int N, int K) {
  __shared__ __align__(16) u16 As[128 * 64];
  __shared__ __align__(16) u16 Bs[128 * 64];
  int tid = threadIdx.x;
  int lane = tid & 63, wid = tid >> 6;
  int wm = wid >> 1, wn = wid & 1;
  int m0 = blockIdx.y * 128, n0 = blockIdx.x * 128;
  f32x4 acc[4][4] = {};
  int srow = tid >> 3, scol = tid & 7;  // staging: row, 16B-chunk
  const u16* Ap = A + (size_t)(m0 + srow) * K + scol * 8;
  const u16* Bp = Bt + (size_t)(n0 + srow) * K + scol * 8;
  u16* Asw = As + srow * 64 + scol * 8;
  u16* Bsw = Bs + srow * 64 + scol * 8;
  for (int k0 = 0; k0 < K; k0 += 64) {
    __syncthreads();
#pragma unroll
    for (int p = 0; p < 4; p++) {
      *(uint4*)(Asw + p * 2048) = *(const uint4*)(Ap + (size_t)(p * 32) * K + k0);
      *(uint4*)(Bsw + p * 2048) = *(const uint4*)(Bp + (size_t)(p * 32) * K + k0);
    }
    __syncthreads();
#pragma unroll
    for (int ks = 0; ks < 2; ks++) {
      bf16x8 a[4], bfr[4];
#pragma unroll
      for (int m = 0; m < 4; m++)
        a[m] = *(const bf16x8*)(As + (wm * 64 + m * 16 + (lane & 15)) * 64 +
                                ks * 32 + (lane >> 4) * 8);
#pragma unroll
      for (int n = 0; n < 4; n++)
        bfr[n] = *(const bf16x8*)(Bs + (wn * 64 + n * 16 + (lane & 15)) * 64 +
                                  ks * 32 + (lane >> 4) * 8);
#pragma unroll
      for (int m = 0; m < 4; m++)
#pragma unroll
        for (int n = 0; n < 4; n++)
          acc[m][n] = __builtin_amdgcn_mfma_f32_16x16x32_bf16(
              a[m], bfr[n], acc[m][n], 0, 0, 0);
    }
  }
#pragma unroll
  for (int m = 0; m < 4; m++)
#pragma unroll
    for (int n = 0; n < 4; n++) {
      int gr0 = m0 + wm * 64 + m * 16 + ((lane >> 4) << 2);
      int gc = n0 + wn * 64 + n * 16 + (lane & 15);
#pragma unroll
      for (int rr = 0; rr < 4; rr++) {
        size_t off = (size_t)(gr0 + rr) * N + gc;
        float val = acc[m][n][rr];
        if (ADD_R) val += R[off];
        C[off] = val;
      }
    }
}

// ---------- fused gate/up MFMA GEMM: act bf16 = silu(A@G) * (A@U) ------------
// 128x64 tile, 4 waves 2x2, wave-tile 64x32 (4x2 frags), dual accumulators.
__global__ __launch_bounds__(256) void gateup_kernel(
    const u16* __restrict__ A, const u16* __restrict__ G,
    const u16* __restrict__ U, u16* __restrict__ act, int M, int N, int K) {
  __shared__ __align__(16) u16 As[128 * 64];
  __shared__ __align__(16) u16 Gs[64 * 64];
  __shared__ __align__(16) u16 Us[64 * 64];
  int tid = threadIdx.x;
  int lane = tid & 63, wid = tid >> 6;
  int wm = wid >> 1, wn = wid & 1;
  int m0 = blockIdx.y * 128, n0 = blockIdx.x * 64;
  f32x4 ag[4][2] = {}, au[4][2] = {};
  int srow = tid >> 3, scol = tid & 7;
  const u16* Ap = A + (size_t)(m0 + srow) * K + scol * 8;
  const u16* Gp = G + (size_t)(n0 + srow) * K + scol * 8;
  const u16* Up = U + (size_t)(n0 + srow) * K + scol * 8;
  u16* Asw = As + srow * 64 + scol * 8;
  u16* Gsw = Gs + srow * 64 + scol * 8;
  u16* Usw = Us + srow * 64 + scol * 8;
  for (int k0 = 0; k0 < K; k0 += 64) {
    __syncthreads();
#pragma unroll
    for (int p = 0; p < 4; p++)
      *(uint4*)(Asw + p * 2048) = *(const uint4*)(Ap + (size_t)(p * 32) * K + k0);
#pragma unroll
    for (int p = 0; p < 2; p++) {
      *(uint4*)(Gsw + p * 2048) = *(const uint4*)(Gp + (size_t)(p * 32) * K + k0);
      *(uint4*)(Usw + p * 2048) = *(const uint4*)(Up + (size_t)(p * 32) * K + k0);
    }
    __syncthreads();
#pragma unroll
    for (int ks = 0; ks < 2; ks++) {
      bf16x8 a[4], g[2], u[2];
#pragma unroll
      for (int m = 0; m < 4; m++)
        a[m] = *(const bf16x8*)(As + (wm * 64 + m * 16 + (lane & 15)) * 64 +
                                ks * 32 + (lane >> 4) * 8);
#pragma unroll
      for (int n = 0; n < 2; n++) {
        g[n] = *(const bf16x8*)(Gs + (wn * 32 + n * 16 + (lane & 15)) * 64 +
                                ks * 32 + (lane >> 4) * 8);
        u[n] = *(const bf16x8*)(Us + (wn * 32 + n * 16 + (lane & 15)) * 64 +
                                ks * 32 + (lane >> 4) * 8);
      }
#pragma unroll
      for (int m = 0; m < 4; m++)
#pragma unroll
        for (int n = 0; n < 2; n++) {
          ag[m][n] = __builtin_amdgcn_mfma_f32_16x16x32_bf16(a[m], g[n],
                                                             ag[m][n], 0, 0, 0);
          au[m][n] = __builtin_amdgcn_mfma_f32_16x16x32_bf16(a[m], u[n],
                                                             au[m][n], 0, 0, 0);
        }
    }
  }
#pragma unroll
  for (int m = 0; m < 4; m++)
#pragma unroll
    for (int n = 0; n < 2; n++) {
      int gr0 = m0 + wm * 64 + m * 16 + ((lane >> 4) << 2);
      int gc = n0 + wn * 32 + n * 16 + (lane & 15);
#pragma unroll
      for (int rr = 0; rr < 4; rr++) {
        float gv = ag[m][n][rr], uv = au[m][n][rr];
        float sv = (gv / (1.f + expf(-gv))) * uv;
        act[(size_t)(gr0 + rr) * N + gc] = f2bf(sv);
      }
    }
}

// ---------- launch -----------------------------------------------------------
extern "C" void kernel_launch(void* const* d_in, const int* in_sizes, int n_in,
                              void* d_out, int out_size, void* d_ws,
                              size_t ws_size, hipStream_t stream) {
  const float* x   = (const float*)d_in[0];
  const float* n1w = (const float*)d_in[1];
  const float* Wq  = (const float*)d_in[2];
  const float* Wk  = (const float*)d_in[3];
  const float* Wv  = (const float*)d_in[4];
  const float* bw  = (const float*)d_in[5];
  const float* bbp = (const float*)d_in[6];
  const float* Wo  = (const float*)d_in[7];
  const float* al  = (const float*)d_in[8];
  const float* n2w = (const float*)d_in[9];
  const float* Wg  = (const float*)d_in[10];
  const float* Wu  = (const float*)d_in[11];
  const float* Wd  = (const float*)d_in[12];
  float* out = (float*)d_out;  // fp32 output
  float* ws = (float*)d_ws;

  // Workspace (floats): A=q[NE] -> actb(bf16,NE*2B); B=k[NE] -> x1;
  // C=v[NE]; E(NE/2 floats)=hb -> ob -> h2b (bf16); W(3M floats)=staged
  // bf16 weights; beta[BT].  Total ~130 MB.
  float* q  = ws;
  float* kk = ws + (size_t)NE;
  float* vv = ws + 2 * (size_t)NE;
  u32*  hb  = (u32*)(ws + 3 * (size_t)NE);           // 16.8 MB bf16 region
  u16*  Wb  = (u16*)(ws + 3 * (size_t)NE + NE / 2);  // 12 MB bf16 weights
  float* beta = ws + 3 * (size_t)NE + NE / 2 + 3 * 1024 * 1024;
  float* x1 = kk;
  u16* actb = (u16*)q;

  dim3 tb(32, 8);
  const int MM = 1024 * 1024;  // D*D elements

  // phase 1: Wq/Wk/Wv -> transposed bf16
  transcvt_kernel<<<dim3(32, 32), tb, 0, stream>>>(Wq, Wb, DD, DD);
  transcvt_kernel<<<dim3(32, 32), tb, 0, stream>>>(Wk, Wb + MM, DD, DD);
  transcvt_kernel<<<dim3(32, 32), tb, 0, stream>>>(Wv, Wb + 2 * MM, DD, DD);

  rmsnorm_bf16_kernel<1><<<BT / 4, 256, 0, stream>>>(x, n1w, bw, bbp, hb, beta);

  dim3 g1(8, 64);  // N/128, M/128
  mgemm_kernel<0><<<g1, 256, 0, stream>>>((const u16*)hb, Wb, nullptr, q,
                                          BT, DD, DD);
  mgemm_kernel<0><<<g1, 256, 0, stream>>>((const u16*)hb, Wb + MM, nullptr, kk,
                                          BT, DD, DD);
  mgemm_kernel<0><<<g1, 256, 0, stream>>>((const u16*)hb, Wb + 2 * MM, nullptr,
                                          vv, BT, DD, DD);
  knorm_kernel<<<BT / 4, 256, 0, stream>>>(kk);
  ema_kernel<<<(BB * DD) / 256, 256, 0, stream>>>(vv, al);

  delta_scan_kernel<<<512, 256, 0, stream>>>(q, kk, vv, beta, hb);  // ob -> E

  // phase 2: Wo
  transcvt_kernel<<<dim3(32, 32), tb, 0, stream>>>(Wo, Wb, DD, DD);
  mgemm_kernel<1><<<g1, 256, 0, stream>>>((const u16*)hb, Wb, x, x1,
                                          BT, DD, DD);

  rmsnorm_bf16_kernel<0><<<BT / 4, 256, 0, stream>>>(x1, n2w, nullptr, nullptr,
                                                     hb, nullptr);

  // phase 3: Wg/Wu/Wd
  const int MH = DD * HH;  // 2M elements
  transcvt_kernel<<<dim3(64, 32), tb, 0, stream>>>(Wg, Wb, DD, HH);
  transcvt_kernel<<<dim3(64, 32), tb, 0, stream>>>(Wu, Wb + MH, DD, HH);
  transcvt_kernel<<<dim3(32, 64), tb, 0, stream>>>(Wd, Wb + 2 * MH, HH, DD);

  gateup_kernel<<<dim3(32, 64), 256, 0, stream>>>((const u16*)hb, Wb, Wb + MH,
                                                  actb, BT, HH, DD);
  mgemm_kernel<1><<<g1, 256, 0, stream>>>(actb, Wb + 2 * MH, x1, out,
                                          BT, DD, HH);
}

// Round 4
// 2658.317 us; speedup vs baseline: 2.0741x; 1.2748x over previous
//
#include <hip/hip_runtime.h>
#include <hip/hip_bf16.h>

#define BB 4
#define TT 2048
#define DD 1024
#define HH 2048
#define NE (BB * TT * DD)   /* 8388608 */
#define BT (BB * TT)        /* 8192 */

typedef unsigned int u32;
typedef unsigned short u16;
typedef __attribute__((ext_vector_type(8))) short bf16x8;
typedef __attribute__((ext_vector_type(4))) float f32x4;

static __device__ __forceinline__ u16 f2bf(float f) {
  u32 u = __float_as_uint(f);
  u32 r = (u + 0x7fffu + ((u >> 16) & 1u)) >> 16;  // RNE
  return (u16)r;
}

static __device__ __forceinline__ float wave_reduce_sum(float v) {
#pragma unroll
  for (int off = 32; off > 0; off >>= 1) v += __shfl_xor(v, off);
  return v;
}

// DPP wave64 sum-reduce entirely on the VALU pipe; full sum lands in lane 63.
#define DPP_STEP(x, ctrl)                                                     \
  x += __uint_as_float(__builtin_amdgcn_update_dpp(                           \
      0, (int)__float_as_uint(x), ctrl, 0xf, 0xf, true))
static __device__ __forceinline__ float dpp_red63(float x) {
  DPP_STEP(x, 0x111);  // row_shr:1
  DPP_STEP(x, 0x112);  // row_shr:2
  DPP_STEP(x, 0x114);  // row_shr:4
  DPP_STEP(x, 0x118);  // row_shr:8  -> lane15 of each 16-row has row sum
  DPP_STEP(x, 0x142);  // row_bcast15 -> lanes 31,63 have pair sums
  DPP_STEP(x, 0x143);  // row_bcast31 -> lane 63 has full sum
  return x;
}

// async 16B global -> LDS (linear dest: wave-uniform base + lane*16)
static __device__ __forceinline__ void gl_lds16(const float* g, float* l) {
  __builtin_amdgcn_global_load_lds(
      (const __attribute__((address_space(1))) void*)g,
      (__attribute__((address_space(3))) void*)l, 16, 0, 0);
}

// ---------- RMSNorm -> bf16 out; optionally fused beta = sigmoid(h.bw+b) ----
template <int WITH_BETA>
__global__ __launch_bounds__(256) void rmsnorm_bf16_kernel(
    const float* __restrict__ x, const float* __restrict__ w,
    const float* __restrict__ bw, const float* __restrict__ bbias,
    u32* __restrict__ hb, float* __restrict__ beta) {
  int row = blockIdx.x * 4 + (threadIdx.x >> 6);
  int lane = threadIdx.x & 63;
  const float4* xr = (const float4*)(x + (size_t)row * DD);
  const float4* wr = (const float4*)w;
  float4 v[4];
  float ss = 0.f;
#pragma unroll
  for (int e = 0; e < 4; e++) {
    v[e] = xr[lane + 64 * e];
    ss += v[e].x * v[e].x + v[e].y * v[e].y + v[e].z * v[e].z + v[e].w * v[e].w;
  }
  ss = wave_reduce_sum(ss);
  float r = rsqrtf(ss * (1.f / DD) + 1e-6f);
  u32* orow = hb + (size_t)row * (DD / 2);
  float p = 0.f;
#pragma unroll
  for (int e = 0; e < 4; e++) {
    float4 wv = wr[lane + 64 * e];
    float hx = v[e].x * r * wv.x, hy = v[e].y * r * wv.y;
    float hz = v[e].z * r * wv.z, hw = v[e].w * r * wv.w;
    uint2 pk;
    pk.x = (u32)f2bf(hx) | ((u32)f2bf(hy) << 16);
    pk.y = (u32)f2bf(hz) | ((u32)f2bf(hw) << 16);
    *(uint2*)(orow + (lane + 64 * e) * 2) = pk;
    if (WITH_BETA) {
      float4 bv = ((const float4*)bw)[lane + 64 * e];
      p += hx * bv.x + hy * bv.y + hz * bv.z + hw * bv.w;
    }
  }
  if (WITH_BETA) {
    p = wave_reduce_sum(p);
    if (lane == 0) beta[row] = 1.f / (1.f + expf(-(p + bbias[0])));
  }
}

// ---------- k row L2-normalize (in place, fp32) ------------------------------
__global__ __launch_bounds__(256) void knorm_kernel(float* __restrict__ k) {
  int row = blockIdx.x * 4 + (threadIdx.x >> 6);
  int lane = threadIdx.x & 63;
  float4* kr = (float4*)(k + (size_t)row * DD);
  float4 v[4];
  float ss = 0.f;
#pragma unroll
  for (int e = 0; e < 4; e++) {
    v[e] = kr[lane + 64 * e];
    ss += v[e].x * v[e].x + v[e].y * v[e].y + v[e].z * v[e].z + v[e].w * v[e].w;
  }
  ss = wave_reduce_sum(ss);
  float r = 1.f / fmaxf(sqrtf(ss), 1e-12f);
#pragma unroll
  for (int e = 0; e < 4; e++) {
    float4 ov;
    ov.x = v[e].x * r; ov.y = v[e].y * r; ov.z = v[e].z * r; ov.w = v[e].w * r;
    kr[lane + 64 * e] = ov;
  }
}

// ---------- EMA over T, one thread per (b,d) chain, in place -----------------
__global__ __launch_bounds__(256) void ema_kernel(
    float* __restrict__ v, const float* __restrict__ alpha_logit) {
  int idx = blockIdx.x * 256 + threadIdx.x;  // 0..4095
  int b = idx >> 10, d = idx & (DD - 1);
  float a = 1.f / (1.f + expf(-alpha_logit[d]));
  float om = 1.f - a;
  float* p = v + (size_t)b * TT * DD + d;
  float s = 0.f;
  for (int t = 0; t < TT; t += 8) {
    float vt[8];
#pragma unroll
    for (int u = 0; u < 8; u++) vt[u] = p[(size_t)(t + u) * DD];
#pragma unroll
    for (int u = 0; u < 8; u++) {
      s = a * vt[u] + om * s;
      p[(size_t)(t + u) * DD] = s;
    }
  }
}

// ---------- delta-rule scan --------------------------------------------------
// 512 blocks x 256 thr; wave = 2 rows, 16 contiguous cols/lane.
// LDS-pipe minimized: 8x ds_read_b128 (XOR chunk swizzle, conflict-free),
// DPP reduce on VALU, global_load_lds staging (no ds_write).
__global__ __launch_bounds__(256) void delta_scan_kernel(
    const float* __restrict__ q, const float* __restrict__ k,
    const float* __restrict__ v, const float* __restrict__ beta,
    u32* __restrict__ ob) {
  __shared__ __align__(16) float kb[2][DD];
  __shared__ __align__(16) float qb[2][DD];
  __shared__ float vb[2][8];
  __shared__ float bb_s[2];
  int wg = blockIdx.x;
  int b = wg >> 7;
  int rb = (wg & 127) * 8;
  int tid = threadIdx.x;
  int wv = tid >> 6, lane = tid & 63;
  int r0 = rb + wv * 2;
  const int sw = (lane >> 1) & 3;
  // fragment float-offsets: chunk u of lane at lane*16 + ((u^sw)*4)
  int fo[4];
#pragma unroll
  for (int u = 0; u < 4; u++) fo[u] = lane * 16 + ((u ^ sw) << 2);
  float s0[16], s1[16];
#pragma unroll
  for (int u = 0; u < 16; u++) { s0[u] = 0.f; s1[u] = 0.f; }
  const size_t base = (size_t)b * TT * DD;
  const size_t base2 = base >> 1;
  // stage t=0
  gl_lds16(k + base + tid * 4, &kb[0][tid * 4]);
  gl_lds16(q + base + tid * 4, &qb[0][tid * 4]);
  if (tid < 8) vb[0][tid] = v[base + rb + tid];
  if (tid == 8) bb_s[0] = beta[b * TT];

  for (int t = 0; t < TT; t++) {
    int buf = t & 1;
    __syncthreads();  // drains each wave's DMA (vmcnt) + orders vb/bb writes
    if (t + 1 < TT) {
      size_t off = base + (size_t)(t + 1) * DD;
      gl_lds16(k + off + tid * 4, &kb[buf ^ 1][tid * 4]);
      gl_lds16(q + off + tid * 4, &qb[buf ^ 1][tid * 4]);
      if (tid < 8) vb[buf ^ 1][tid] = v[off + rb + tid];
      if (tid == 8) bb_s[buf ^ 1] = beta[b * TT + t + 1];
    }
    float kk[16], qq[16];
#pragma unroll
    for (int u = 0; u < 4; u++) {
      *(float4*)&kk[u * 4] = *(const float4*)&kb[buf][fo[u]];
      *(float4*)&qq[u * 4] = *(const float4*)&qb[buf][fo[u]];
    }
    float pa0 = 0.f, pa1 = 0.f, pq0 = 0.f, pq1 = 0.f, kq = 0.f;
#pragma unroll
    for (int u = 0; u < 16; u++) {
      pa0 = fmaf(s0[u], kk[u], pa0);
      pa1 = fmaf(s1[u], kk[u], pa1);
      pq0 = fmaf(s0[u], qq[u], pq0);
      pq1 = fmaf(s1[u], qq[u], pq1);
      kq  = fmaf(kk[u], qq[u], kq);
    }
    pa0 = dpp_red63(pa0);
    pa1 = dpp_red63(pa1);
    pq0 = dpp_red63(pq0);
    pq1 = dpp_red63(pq1);
    kq  = dpp_red63(kq);
    float pa0b = __uint_as_float(
        __builtin_amdgcn_readlane((int)__float_as_uint(pa0), 63));
    float pa1b = __uint_as_float(
        __builtin_amdgcn_readlane((int)__float_as_uint(pa1), 63));
    float bt = bb_s[buf];
    float c0 = bt * (vb[buf][wv * 2] - pa0b);
    float c1 = bt * (vb[buf][wv * 2 + 1] - pa1b);
#pragma unroll
    for (int u = 0; u < 16; u++) {
      s0[u] = fmaf(c0, kk[u], s0[u]);
      s1[u] = fmaf(c1, kk[u], s1[u]);
    }
    if (lane == 63) {  // pq0/pq1/kq full sums live in lane 63
      float o0 = pq0 + c0 * kq;
      float o1 = pq1 + c1 * kq;
      ob[base2 + (size_t)t * (DD / 2) + (r0 >> 1)] =
          (u32)f2bf(o0) | ((u32)f2bf(o1) << 16);
    }
  }
}

// ---------- transpose + fp32->bf16 weight convert: Wt[n][k] = W[k][n] --------
__global__ void transcvt_kernel(const float* __restrict__ W,
                                u16* __restrict__ Wt, int K, int N) {
  __shared__ float tile[32][33];
  int tx = threadIdx.x, ty = threadIdx.y;  // (32,8)
  int n0 = blockIdx.x * 32, k0 = blockIdx.y * 32;
#pragma unroll
  for (int i = 0; i < 4; i++)
    tile[ty + i * 8][tx] = W[(size_t)(k0 + ty + i * 8) * N + n0 + tx];
  __syncthreads();
#pragma unroll
  for (int i = 0; i < 4; i++)
    Wt[(size_t)(n0 + ty + i * 8) * K + k0 + tx] = f2bf(tile[tx][ty + i * 8]);
}

// ---------- bf16 MFMA GEMM: C(M,N) fp32 = A(M,K)bf16 @ Bt(N,K)bf16 (+R) ------
// 128x128 tile, BK=64, 4 waves 2x2, wave-tile 64x64 (4x4 frags of 16x16x32).
template <int ADD_R>
__global__ __launch_bounds__(256) void mgemm_kernel(
    const u16* __restrict__ A, const u16* __restrict__ Bt,
    const float* __restrict__ R, float* __restrict__ C,
    int M, int N, int K) {
  __shared__ __align__(16) u16 As[128 * 64];
  __shared__ __align__(16) u16 Bs[128 * 64];
  int tid = threadIdx.x;
  int lane = tid & 63, wid = tid >> 6;
  int wm = wid >> 1, wn = wid & 1;
  int m0 = blockIdx.y * 128, n0 = blockIdx.x * 128;
  f32x4 acc[4][4] = {};
  int srow = tid >> 3, scol = tid & 7;  // staging: row, 16B-chunk
  const u16* Ap = A + (size_t)(m0 + srow) * K + scol * 8;
  const u16* Bp = Bt + (size_t)(n0 + srow) * K + scol * 8;
  u16* Asw = As + srow * 64 + scol * 8;
  u16* Bsw = Bs + srow * 64 + scol * 8;
  for (int k0 = 0; k0 < K; k0 += 64) {
    __syncthreads();
#pragma unroll
    for (int p = 0; p < 4; p++) {
      *(uint4*)(Asw + p * 2048) = *(const uint4*)(Ap + (size_t)(p * 32) * K + k0);
      *(uint4*)(Bsw + p * 2048) = *(const uint4*)(Bp + (size_t)(p * 32) * K + k0);
    }
    __syncthreads();
#pragma unroll
    for (int ks = 0; ks < 2; ks++) {
      bf16x8 a[4], bfr[4];
#pragma unroll
      for (int m = 0; m < 4; m++)
        a[m] = *(const bf16x8*)(As + (wm * 64 + m * 16 + (lane & 15)) * 64 +
                                ks * 32 + (lane >> 4) * 8);
#pragma unroll
      for (int n = 0; n < 4; n++)
        bfr[n] = *(const bf16x8*)(Bs + (wn * 64 + n * 16 + (lane & 15)) * 64 +
                                  ks * 32 + (lane >> 4) * 8);
#pragma unroll
      for (int m = 0; m < 4; m++)
#pragma unroll
        for (int n = 0; n < 4; n++)
          acc[m][n] = __builtin_amdgcn_mfma_f32_16x16x32_bf16(
              a[m], bfr[n], acc[m][n], 0, 0, 0);
    }
  }
#pragma unroll
  for (int m = 0; m < 4; m++)
#pragma unroll
    for (int n = 0; n < 4; n++) {
      int gr0 = m0 + wm * 64 + m * 16 + ((lane >> 4) << 2);
      int gc = n0 + wn * 64 + n * 16 + (lane & 15);
#pragma unroll
      for (int rr = 0; rr < 4; rr++) {
        size_t off = (size_t)(gr0 + rr) * N + gc;
        float val = acc[m][n][rr];
        if (ADD_R) val += R[off];
        C[off] = val;
      }
    }
}

// ---------- fused gate/up MFMA GEMM: act bf16 = silu(A@G) * (A@U) ------------
// 128x64 tile, 4 waves 2x2, wave-tile 64x32 (4x2 frags), dual accumulators.
__global__ __launch_bounds__(256) void gateup_kernel(
    const u16* __restrict__ A, const u16* __restrict__ G,
    const u16* __restrict__ U, u16* __restrict__ act, int M, int N, int K) {
  __shared__ __align__(16) u16 As[128 * 64];
  __shared__ __align__(16) u16 Gs[64 * 64];
  __shared__ __align__(16) u16 Us[64 * 64];
  int tid = threadIdx.x;
  int lane = tid & 63, wid = tid >> 6;
  int wm = wid >> 1, wn = wid & 1;
  int m0 = blockIdx.y * 128, n0 = blockIdx.x * 64;
  f32x4 ag[4][2] = {}, au[4][2] = {};
  int srow = tid >> 3, scol = tid & 7;
  const u16* Ap = A + (size_t)(m0 + srow) * K + scol * 8;
  const u16* Gp = G + (size_t)(n0 + srow) * K + scol * 8;
  const u16* Up = U + (size_t)(n0 + srow) * K + scol * 8;
  u16* Asw = As + srow * 64 + scol * 8;
  u16* Gsw = Gs + srow * 64 + scol * 8;
  u16* Usw = Us + srow * 64 + scol * 8;
  for (int k0 = 0; k0 < K; k0 += 64) {
    __syncthreads();
#pragma unroll
    for (int p = 0; p < 4; p++)
      *(uint4*)(Asw + p * 2048) = *(const uint4*)(Ap + (size_t)(p * 32) * K + k0);
#pragma unroll
    for (int p = 0; p < 2; p++) {
      *(uint4*)(Gsw + p * 2048) = *(const uint4*)(Gp + (size_t)(p * 32) * K + k0);
      *(uint4*)(Usw + p * 2048) = *(const uint4*)(Up + (size_t)(p * 32) * K + k0);
    }
    __syncthreads();
#pragma unroll
    for (int ks = 0; ks < 2; ks++) {
      bf16x8 a[4], g[2], u[2];
#pragma unroll
      for (int m = 0; m < 4; m++)
        a[m] = *(const bf16x8*)(As + (wm * 64 + m * 16 + (lane & 15)) * 64 +
                                ks * 32 + (lane >> 4) * 8);
#pragma unroll
      for (int n = 0; n < 2; n++) {
        g[n] = *(const bf16x8*)(Gs + (wn * 32 + n * 16 + (lane & 15)) * 64 +
                                ks * 32 + (lane >> 4) * 8);
        u[n] = *(const bf16x8*)(Us + (wn * 32 + n * 16 + (lane & 15)) * 64 +
                                ks * 32 + (lane >> 4) * 8);
      }
#pragma unroll
      for (int m = 0; m < 4; m++)
#pragma unroll
        for (int n = 0; n < 2; n++) {
          ag[m][n] = __builtin_amdgcn_mfma_f32_16x16x32_bf16(a[m], g[n],
                                                             ag[m][n], 0, 0, 0);
          au[m][n] = __builtin_amdgcn_mfma_f32_16x16x32_bf16(a[m], u[n],
                                                             au[m][n], 0, 0, 0);
        }
    }
  }
#pragma unroll
  for (int m = 0; m < 4; m++)
#pragma unroll
    for (int n = 0; n < 2; n++) {
      int gr0 = m0 + wm * 64 + m * 16 + ((lane >> 4) << 2);
      int gc = n0 + wn * 32 + n * 16 + (lane & 15);
#pragma unroll
      for (int rr = 0; rr < 4; rr++) {
        float gv = ag[m][n][rr], uv = au[m][n][rr];
        float sv = (gv / (1.f + expf(-gv))) * uv;
        act[(size_t)(gr0 + rr) * N + gc] = f2bf(sv);
      }
    }
}

// ---------- launch -----------------------------------------------------------
extern "C" void kernel_launch(void* const* d_in, const int* in_sizes, int n_in,
                              void* d_out, int out_size, void* d_ws,
                              size_t ws_size, hipStream_t stream) {
  const float* x   = (const float*)d_in[0];
  const float* n1w = (const float*)d_in[1];
  const float* Wq  = (const float*)d_in[2];
  const float* Wk  = (const float*)d_in[3];
  const float* Wv  = (const float*)d_in[4];
  const float* bw  = (const float*)d_in[5];
  const float* bbp = (const float*)d_in[6];
  const float* Wo  = (const float*)d_in[7];
  const float* al  = (const float*)d_in[8];
  const float* n2w = (const float*)d_in[9];
  const float* Wg  = (const float*)d_in[10];
  const float* Wu  = (const float*)d_in[11];
  const float* Wd  = (const float*)d_in[12];
  float* out = (float*)d_out;  // fp32 output
  float* ws = (float*)d_ws;

  // Workspace (floats): A=q[NE] -> actb(bf16); B=k[NE] -> x1; C=v[NE];
  // E(NE/2 floats)=hb -> ob -> h2b (bf16); W=staged bf16 weights; beta[BT].
  float* q  = ws;
  float* kk = ws + (size_t)NE;
  float* vv = ws + 2 * (size_t)NE;
  u32*  hb  = (u32*)(ws + 3 * (size_t)NE);           // 16.8 MB bf16 region
  u16*  Wb  = (u16*)(ws + 3 * (size_t)NE + NE / 2);  // 12 MB bf16 weights
  float* beta = ws + 3 * (size_t)NE + NE / 2 + 3 * 1024 * 1024;
  float* x1 = kk;
  u16* actb = (u16*)q;

  dim3 tb(32, 8);
  const int MM = 1024 * 1024;  // D*D elements

  // phase 1: Wq/Wk/Wv -> transposed bf16
  transcvt_kernel<<<dim3(32, 32), tb, 0, stream>>>(Wq, Wb, DD, DD);
  transcvt_kernel<<<dim3(32, 32), tb, 0, stream>>>(Wk, Wb + MM, DD, DD);
  transcvt_kernel<<<dim3(32, 32), tb, 0, stream>>>(Wv, Wb + 2 * MM, DD, DD);

  rmsnorm_bf16_kernel<1><<<BT / 4, 256, 0, stream>>>(x, n1w, bw, bbp, hb, beta);

  dim3 g1(8, 64);  // N/128, M/128
  mgemm_kernel<0><<<g1, 256, 0, stream>>>((const u16*)hb, Wb, nullptr, q,
                                          BT, DD, DD);
  mgemm_kernel<0><<<g1, 256, 0, stream>>>((const u16*)hb, Wb + MM, nullptr, kk,
                                          BT, DD, DD);
  mgemm_kernel<0><<<g1, 256, 0, stream>>>((const u16*)hb, Wb + 2 * MM, nullptr,
                                          vv, BT, DD, DD);
  knorm_kernel<<<BT / 4, 256, 0, stream>>>(kk);
  ema_kernel<<<(BB * DD) / 256, 256, 0, stream>>>(vv, al);

  delta_scan_kernel<<<512, 256, 0, stream>>>(q, kk, vv, beta, hb);  // ob -> E

  // phase 2: Wo
  transcvt_kernel<<<dim3(32, 32), tb, 0, stream>>>(Wo, Wb, DD, DD);
  mgemm_kernel<1><<<g1, 256, 0, stream>>>((const u16*)hb, Wb, x, x1,
                                          BT, DD, DD);

  rmsnorm_bf16_kernel<0><<<BT / 4, 256, 0, stream>>>(x1, n2w, nullptr, nullptr,
                                                     hb, nullptr);

  // phase 3: Wg/Wu/Wd
  const int MH = DD * HH;  // 2M elements
  transcvt_kernel<<<dim3(64, 32), tb, 0, stream>>>(Wg, Wb, DD, HH);
  transcvt_kernel<<<dim3(64, 32), tb, 0, stream>>>(Wu, Wb + MH, DD, HH);
  transcvt_kernel<<<dim3(32, 64), tb, 0, stream>>>(Wd, Wb + 2 * MH, HH, DD);

  gateup_kernel<<<dim3(32, 64), 256, 0, stream>>>((const u16*)hb, Wb, Wb + MH,
                                                  actb, BT, HH, DD);
  mgemm_kernel<1><<<g1, 256, 0, stream>>>(actb, Wb + 2 * MH, x1, out,
                                          BT, DD, HH);
}

// Round 5
// 2365.530 us; speedup vs baseline: 2.3308x; 1.1238x over previous
//
#include <hip/hip_runtime.h>
#include <hip/hip_bf16.h>

#define BB 4
#define TT 2048
#define DD 1024
#define HH 2048
#define NE (BB * TT * DD)   /* 8388608 */
#define BT (BB * TT)        /* 8192 */

typedef unsigned int u32;
typedef unsigned short u16;
typedef __attribute__((ext_vector_type(8))) short bf16x8;
typedef __attribute__((ext_vector_type(4))) float f32x4;

static __device__ __forceinline__ u16 f2bf(float f) {
  u32 u = __float_as_uint(f);
  u32 r = (u + 0x7fffu + ((u >> 16) & 1u)) >> 16;  // RNE
  return (u16)r;
}

static __device__ __forceinline__ float wave_reduce_sum(float v) {
#pragma unroll
  for (int off = 32; off > 0; off >>= 1) v += __shfl_xor(v, off);
  return v;
}

// DPP wave64 sum-reduce entirely on the VALU pipe; full sum lands in lane 63.
#define DPP_STEP(x, ctrl)                                                     \
  x += __uint_as_float(__builtin_amdgcn_update_dpp(                           \
      0, (int)__float_as_uint(x), ctrl, 0xf, 0xf, true))
static __device__ __forceinline__ float dpp_red63(float x) {
  DPP_STEP(x, 0x111);  // row_shr:1
  DPP_STEP(x, 0x112);  // row_shr:2
  DPP_STEP(x, 0x114);  // row_shr:4
  DPP_STEP(x, 0x118);  // row_shr:8  -> lane15 of each 16-row has row sum
  DPP_STEP(x, 0x142);  // row_bcast15 -> lanes 31,63 have pair sums
  DPP_STEP(x, 0x143);  // row_bcast31 -> lane 63 has full sum
  return x;
}

// async 16B global -> LDS (linear dest: wave-uniform base + lane*16)
static __device__ __forceinline__ void gl_lds16(const float* g, float* l) {
  __builtin_amdgcn_global_load_lds(
      (const __attribute__((address_space(1))) void*)g,
      (__attribute__((address_space(3))) void*)l, 16, 0, 0);
}

// ---------- RMSNorm -> bf16 out; optionally fused beta = sigmoid(h.bw+b) ----
template <int WITH_BETA>
__global__ __launch_bounds__(256) void rmsnorm_bf16_kernel(
    const float* __restrict__ x, const float* __restrict__ w,
    const float* __restrict__ bw, const float* __restrict__ bbias,
    u32* __restrict__ hb, float* __restrict__ beta) {
  int row = blockIdx.x * 4 + (threadIdx.x >> 6);
  int lane = threadIdx.x & 63;
  const float4* xr = (const float4*)(x + (size_t)row * DD);
  const float4* wr = (const float4*)w;
  float4 v[4];
  float ss = 0.f;
#pragma unroll
  for (int e = 0; e < 4; e++) {
    v[e] = xr[lane + 64 * e];
    ss += v[e].x * v[e].x + v[e].y * v[e].y + v[e].z * v[e].z + v[e].w * v[e].w;
  }
  ss = wave_reduce_sum(ss);
  float r = rsqrtf(ss * (1.f / DD) + 1e-6f);
  u32* orow = hb + (size_t)row * (DD / 2);
  float p = 0.f;
#pragma unroll
  for (int e = 0; e < 4; e++) {
    float4 wv = wr[lane + 64 * e];
    float hx = v[e].x * r * wv.x, hy = v[e].y * r * wv.y;
    float hz = v[e].z * r * wv.z, hw = v[e].w * r * wv.w;
    uint2 pk;
    pk.x = (u32)f2bf(hx) | ((u32)f2bf(hy) << 16);
    pk.y = (u32)f2bf(hz) | ((u32)f2bf(hw) << 16);
    *(uint2*)(orow + (lane + 64 * e) * 2) = pk;
    if (WITH_BETA) {
      float4 bv = ((const float4*)bw)[lane + 64 * e];
      p += hx * bv.x + hy * bv.y + hz * bv.z + hw * bv.w;
    }
  }
  if (WITH_BETA) {
    p = wave_reduce_sum(p);
    if (lane == 0) beta[row] = 1.f / (1.f + expf(-(p + bbias[0])));
  }
}

// ---------- k row L2-normalize (in place, fp32) ------------------------------
__global__ __launch_bounds__(256) void knorm_kernel(float* __restrict__ k) {
  int row = blockIdx.x * 4 + (threadIdx.x >> 6);
  int lane = threadIdx.x & 63;
  float4* kr = (float4*)(k + (size_t)row * DD);
  float4 v[4];
  float ss = 0.f;
#pragma unroll
  for (int e = 0; e < 4; e++) {
    v[e] = kr[lane + 64 * e];
    ss += v[e].x * v[e].x + v[e].y * v[e].y + v[e].z * v[e].z + v[e].w * v[e].w;
  }
  ss = wave_reduce_sum(ss);
  float r = 1.f / fmaxf(sqrtf(ss), 1e-12f);
#pragma unroll
  for (int e = 0; e < 4; e++) {
    float4 ov;
    ov.x = v[e].x * r; ov.y = v[e].y * r; ov.z = v[e].z * r; ov.w = v[e].w * r;
    kr[lane + 64 * e] = ov;
  }
}

// ---------- EMA over T, one thread per (b,d) chain, in place -----------------
__global__ __launch_bounds__(256) void ema_kernel(
    float* __restrict__ v, const float* __restrict__ alpha_logit) {
  int idx = blockIdx.x * 256 + threadIdx.x;  // 0..4095
  int b = idx >> 10, d = idx & (DD - 1);
  float a = 1.f / (1.f + expf(-alpha_logit[d]));
  float om = 1.f - a;
  float* p = v + (size_t)b * TT * DD + d;
  float s = 0.f;
  for (int t = 0; t < TT; t += 8) {
    float vt[8];
#pragma unroll
    for (int u = 0; u < 8; u++) vt[u] = p[(size_t)(t + u) * DD];
#pragma unroll
    for (int u = 0; u < 8; u++) {
      s = a * vt[u] + om * s;
      p[(size_t)(t + u) * DD] = s;
    }
  }
}

// ---------- delta-rule scan --------------------------------------------------
// 512 blocks x 256 thr; wave = 2 rows. Lane owns cols {u*256 + lane*4 + w}:
// ds_read_b128 at byte u*1024 + lane*16 -> canonical contiguous, conflict-free.
// Two timesteps staged per buffer -> one barrier per 2 steps.
__global__ __launch_bounds__(256) void delta_scan_kernel(
    const float* __restrict__ q, const float* __restrict__ k,
    const float* __restrict__ v, const float* __restrict__ beta,
    u32* __restrict__ ob) {
  __shared__ __align__(16) float kb[2][2][DD];
  __shared__ __align__(16) float qb[2][2][DD];
  __shared__ float vb[2][2][8];
  __shared__ float bb_s[2][2];
  int wg = blockIdx.x;
  int b = wg >> 7;
  int rb = (wg & 127) * 8;
  int tid = threadIdx.x;
  int wv = tid >> 6, lane = tid & 63;
  int r0 = rb + wv * 2;
  float s0[16], s1[16];
#pragma unroll
  for (int u = 0; u < 16; u++) { s0[u] = 0.f; s1[u] = 0.f; }
  const size_t base = (size_t)b * TT * DD;
  const size_t base2 = base >> 1;

  // stage timestep pair (t, t+1) into buffer nb
  auto STAGE = [&](int nb, int t) {
    size_t off0 = base + (size_t)t * DD;
    gl_lds16(k + off0 + tid * 4, &kb[nb][0][tid * 4]);
    gl_lds16(q + off0 + tid * 4, &qb[nb][0][tid * 4]);
    gl_lds16(k + off0 + DD + tid * 4, &kb[nb][1][tid * 4]);
    gl_lds16(q + off0 + DD + tid * 4, &qb[nb][1][tid * 4]);
    if (tid < 8) {
      vb[nb][0][tid] = v[off0 + rb + tid];
      vb[nb][1][tid] = v[off0 + DD + rb + tid];
    }
    if (tid == 8) {
      bb_s[nb][0] = beta[b * TT + t];
      bb_s[nb][1] = beta[b * TT + t + 1];
    }
  };

  STAGE(0, 0);
  for (int t = 0; t < TT; t += 2) {
    int buf = (t >> 1) & 1;
    __syncthreads();  // drains DMA (vmcnt) + separates reads from overwrite
    if (t + 2 < TT) STAGE(buf ^ 1, t + 2);
#pragma unroll
    for (int s = 0; s < 2; s++) {
      float kk[16], qq[16];
#pragma unroll
      for (int u = 0; u < 4; u++) {
        *(float4*)&kk[u * 4] = *(const float4*)&kb[buf][s][u * 256 + lane * 4];
        *(float4*)&qq[u * 4] = *(const float4*)&qb[buf][s][u * 256 + lane * 4];
      }
      float pa0 = 0.f, pa1 = 0.f, pq0 = 0.f, pq1 = 0.f, kq = 0.f;
#pragma unroll
      for (int u = 0; u < 16; u++) {
        pa0 = fmaf(s0[u], kk[u], pa0);
        pa1 = fmaf(s1[u], kk[u], pa1);
        pq0 = fmaf(s0[u], qq[u], pq0);
        pq1 = fmaf(s1[u], qq[u], pq1);
        kq  = fmaf(kk[u], qq[u], kq);
      }
      pa0 = dpp_red63(pa0);
      pa1 = dpp_red63(pa1);
      pq0 = dpp_red63(pq0);
      pq1 = dpp_red63(pq1);
      kq  = dpp_red63(kq);
      float pa0b = __uint_as_float(
          __builtin_amdgcn_readlane((int)__float_as_uint(pa0), 63));
      float pa1b = __uint_as_float(
          __builtin_amdgcn_readlane((int)__float_as_uint(pa1), 63));
      float bt = bb_s[buf][s];
      float c0 = bt * (vb[buf][s][wv * 2] - pa0b);
      float c1 = bt * (vb[buf][s][wv * 2 + 1] - pa1b);
#pragma unroll
      for (int u = 0; u < 16; u++) {
        s0[u] = fmaf(c0, kk[u], s0[u]);
        s1[u] = fmaf(c1, kk[u], s1[u]);
      }
      if (lane == 63) {  // pq0/pq1/kq full sums live in lane 63
        float o0 = pq0 + c0 * kq;
        float o1 = pq1 + c1 * kq;
        ob[base2 + (size_t)(t + s) * (DD / 2) + (r0 >> 1)] =
            (u32)f2bf(o0) | ((u32)f2bf(o1) << 16);
      }
    }
  }
}

// ---------- transpose + fp32->bf16 weight convert: Wt[n][k] = W[k][n] --------
__global__ void transcvt_kernel(const float* __restrict__ W,
                                u16* __restrict__ Wt, int K, int N) {
  __shared__ float tile[32][33];
  int tx = threadIdx.x, ty = threadIdx.y;  // (32,8)
  int n0 = blockIdx.x * 32, k0 = blockIdx.y * 32;
#pragma unroll
  for (int i = 0; i < 4; i++)
    tile[ty + i * 8][tx] = W[(size_t)(k0 + ty + i * 8) * N + n0 + tx];
  __syncthreads();
#pragma unroll
  for (int i = 0; i < 4; i++)
    Wt[(size_t)(n0 + ty + i * 8) * K + k0 + tx] = f2bf(tile[tx][ty + i * 8]);
}

// ---------- bf16 MFMA GEMM: C(M,N) fp32 = A(M,K)bf16 @ Bt(N,K)bf16 (+R) ------
// 128x128 tile, BK=64, 4 waves 2x2, wave-tile 64x64 (4x4 frags of 16x16x32).
template <int ADD_R>
__global__ __launch_bounds__(256) void mgemm_kernel(
    const u16* __restrict__ A, const u16* __restrict__ Bt,
    const float* __restrict__ R, float* __restrict__ C,
    int M, int N, int K) {
  __shared__ __align__(16) u16 As[128 * 64];
  __shared__ __align__(16) u16 Bs[128 * 64];
  int tid = threadIdx.x;
  int lane = tid & 63, wid = tid >> 6;
  int wm = wid >> 1, wn = wid & 1;
  int m0 = blockIdx.y * 128, n0 = blockIdx.x * 128;
  f32x4 acc[4][4] = {};
  int srow = tid >> 3, scol = tid & 7;  // staging: row, 16B-chunk
  const u16* Ap = A + (size_t)(m0 + srow) * K + scol * 8;
  const u16* Bp = Bt + (size_t)(n0 + srow) * K + scol * 8;
  u16* Asw = As + srow * 64 + scol * 8;
  u16* Bsw = Bs + srow * 64 + scol * 8;
  for (int k0 = 0; k0 < K; k0 += 64) {
    __syncthreads();
#pragma unroll
    for (int p = 0; p < 4; p++) {
      *(uint4*)(Asw + p * 2048) = *(const uint4*)(Ap + (size_t)(p * 32) * K + k0);
      *(uint4*)(Bsw + p * 2048) = *(const uint4*)(Bp + (size_t)(p * 32) * K + k0);
    }
    __syncthreads();
#pragma unroll
    for (int ks = 0; ks < 2; ks++) {
      bf16x8 a[4], bfr[4];
#pragma unroll
      for (int m = 0; m < 4; m++)
        a[m] = *(const bf16x8*)(As + (wm * 64 + m * 16 + (lane & 15)) * 64 +
                                ks * 32 + (lane >> 4) * 8);
#pragma unroll
      for (int n = 0; n < 4; n++)
        bfr[n] = *(const bf16x8*)(Bs + (wn * 64 + n * 16 + (lane & 15)) * 64 +
                                  ks * 32 + (lane >> 4) * 8);
#pragma unroll
      for (int m = 0; m < 4; m++)
#pragma unroll
        for (int n = 0; n < 4; n++)
          acc[m][n] = __builtin_amdgcn_mfma_f32_16x16x32_bf16(
              a[m], bfr[n], acc[m][n], 0, 0, 0);
    }
  }
#pragma unroll
  for (int m = 0; m < 4; m++)
#pragma unroll
    for (int n = 0; n < 4; n++) {
      int gr0 = m0 + wm * 64 + m * 16 + ((lane >> 4) << 2);
      int gc = n0 + wn * 64 + n * 16 + (lane & 15);
#pragma unroll
      for (int rr = 0; rr < 4; rr++) {
        size_t off = (size_t)(gr0 + rr) * N + gc;
        float val = acc[m][n][rr];
        if (ADD_R) val += R[off];
        C[off] = val;
      }
    }
}

// ---------- fused gate/up MFMA GEMM: act bf16 = silu(A@G) * (A@U) ------------
// 128x64 tile, 4 waves 2x2, wave-tile 64x32 (4x2 frags), dual accumulators.
__global__ __launch_bounds__(256) void gateup_kernel(
    const u16* __restrict__ A, const u16* __restrict__ G,
    const u16* __restrict__ U, u16* __restrict__ act, int M, int N, int K) {
  __shared__ __align__(16) u16 As[128 * 64];
  __shared__ __align__(16) u16 Gs[64 * 64];
  __shared__ __align__(16) u16 Us[64 * 64];
  int tid = threadIdx.x;
  int lane = tid & 63, wid = tid >> 6;
  int wm = wid >> 1, wn = wid & 1;
  int m0 = blockIdx.y * 128, n0 = blockIdx.x * 64;
  f32x4 ag[4][2] = {}, au[4][2] = {};
  int srow = tid >> 3, scol = tid & 7;
  const u16* Ap = A + (size_t)(m0 + srow) * K + scol * 8;
  const u16* Gp = G + (size_t)(n0 + srow) * K + scol * 8;
  const u16* Up = U + (size_t)(n0 + srow) * K + scol * 8;
  u16* Asw = As + srow * 64 + scol * 8;
  u16* Gsw = Gs + srow * 64 + scol * 8;
  u16* Usw = Us + srow * 64 + scol * 8;
  for (int k0 = 0; k0 < K; k0 += 64) {
    __syncthreads();
#pragma unroll
    for (int p = 0; p < 4; p++)
      *(uint4*)(Asw + p * 2048) = *(const uint4*)(Ap + (size_t)(p * 32) * K + k0);
#pragma unroll
    for (int p = 0; p < 2; p++) {
      *(uint4*)(Gsw + p * 2048) = *(const uint4*)(Gp + (size_t)(p * 32) * K + k0);
      *(uint4*)(Usw + p * 2048) = *(const uint4*)(Up + (size_t)(p * 32) * K + k0);
    }
    __syncthreads();
#pragma unroll
    for (int ks = 0; ks < 2; ks++) {
      bf16x8 a[4], g[2], u[2];
#pragma unroll
      for (int m = 0; m < 4; m++)
        a[m] = *(const bf16x8*)(As + (wm * 64 + m * 16 + (lane & 15)) * 64 +
                                ks * 32 + (lane >> 4) * 8);
#pragma unroll
      for (int n = 0; n < 2; n++) {
        g[n] = *(const bf16x8*)(Gs + (wn * 32 + n * 16 + (lane & 15)) * 64 +
                                ks * 32 + (lane >> 4) * 8);
        u[n] = *(const bf16x8*)(Us + (wn * 32 + n * 16 + (lane & 15)) * 64 +
                                ks * 32 + (lane >> 4) * 8);
      }
#pragma unroll
      for (int m = 0; m < 4; m++)
#pragma unroll
        for (int n = 0; n < 2; n++) {
          ag[m][n] = __builtin_amdgcn_mfma_f32_16x16x32_bf16(a[m], g[n],
                                                             ag[m][n], 0, 0, 0);
          au[m][n] = __builtin_amdgcn_mfma_f32_16x16x32_bf16(a[m], u[n],
                                                             au[m][n], 0, 0, 0);
        }
    }
  }
#pragma unroll
  for (int m = 0; m < 4; m++)
#pragma unroll
    for (int n = 0; n < 2; n++) {
      int gr0 = m0 + wm * 64 + m * 16 + ((lane >> 4) << 2);
      int gc = n0 + wn * 32 + n * 16 + (lane & 15);
#pragma unroll
      for (int rr = 0; rr < 4; rr++) {
        float gv = ag[m][n][rr], uv = au[m][n][rr];
        float sv = (gv / (1.f + expf(-gv))) * uv;
        act[(size_t)(gr0 + rr) * N + gc] = f2bf(sv);
      }
    }
}

// ---------- launch -----------------------------------------------------------
extern "C" void kernel_launch(void* const* d_in, const int* in_sizes, int n_in,
                              void* d_out, int out_size, void* d_ws,
                              size_t ws_size, hipStream_t stream) {
  const float* x   = (const float*)d_in[0];
  const float* n1w = (const float*)d_in[1];
  const float* Wq  = (const float*)d_in[2];
  const float* Wk  = (const float*)d_in[3];
  const float* Wv  = (const float*)d_in[4];
  const float* bw  = (const float*)d_in[5];
  const float* bbp = (const float*)d_in[6];
  const float* Wo  = (const float*)d_in[7];
  const float* al  = (const float*)d_in[8];
  const float* n2w = (const float*)d_in[9];
  const float* Wg  = (const float*)d_in[10];
  const float* Wu  = (const float*)d_in[11];
  const float* Wd  = (const float*)d_in[12];
  float* out = (float*)d_out;  // fp32 output
  float* ws = (float*)d_ws;

  // Workspace (floats): A=q[NE] -> actb(bf16); B=k[NE] -> x1; C=v[NE];
  // E(NE/2 floats)=hb -> ob -> h2b (bf16); W=staged bf16 weights; beta[BT].
  float* q  = ws;
  float* kk = ws + (size_t)NE;
  float* vv = ws + 2 * (size_t)NE;
  u32*  hb  = (u32*)(ws + 3 * (size_t)NE);           // 16.8 MB bf16 region
  u16*  Wb  = (u16*)(ws + 3 * (size_t)NE + NE / 2);  // 12 MB bf16 weights
  float* beta = ws + 3 * (size_t)NE + NE / 2 + 3 * 1024 * 1024;
  float* x1 = kk;
  u16* actb = (u16*)q;

  dim3 tb(32, 8);
  const int MM = 1024 * 1024;  // D*D elements

  // phase 1: Wq/Wk/Wv -> transposed bf16
  transcvt_kernel<<<dim3(32, 32), tb, 0, stream>>>(Wq, Wb, DD, DD);
  transcvt_kernel<<<dim3(32, 32), tb, 0, stream>>>(Wk, Wb + MM, DD, DD);
  transcvt_kernel<<<dim3(32, 32), tb, 0, stream>>>(Wv, Wb + 2 * MM, DD, DD);

  rmsnorm_bf16_kernel<1><<<BT / 4, 256, 0, stream>>>(x, n1w, bw, bbp, hb, beta);

  dim3 g1(8, 64);  // N/128, M/128
  mgemm_kernel<0><<<g1, 256, 0, stream>>>((const u16*)hb, Wb, nullptr, q,
                                          BT, DD, DD);
  mgemm_kernel<0><<<g1, 256, 0, stream>>>((const u16*)hb, Wb + MM, nullptr, kk,
                                          BT, DD, DD);
  mgemm_kernel<0><<<g1, 256, 0, stream>>>((const u16*)hb, Wb + 2 * MM, nullptr,
                                          vv, BT, DD, DD);
  knorm_kernel<<<BT / 4, 256, 0, stream>>>(kk);
  ema_kernel<<<(BB * DD) / 256, 256, 0, stream>>>(vv, al);

  delta_scan_kernel<<<512, 256, 0, stream>>>(q, kk, vv, beta, hb);  // ob -> E

  // phase 2: Wo
  transcvt_kernel<<<dim3(32, 32), tb, 0, stream>>>(Wo, Wb, DD, DD);
  mgemm_kernel<1><<<g1, 256, 0, stream>>>((const u16*)hb, Wb, x, x1,
                                          BT, DD, DD);

  rmsnorm_bf16_kernel<0><<<BT / 4, 256, 0, stream>>>(x1, n2w, nullptr, nullptr,
                                                     hb, nullptr);

  // phase 3: Wg/Wu/Wd
  const int MH = DD * HH;  // 2M elements
  transcvt_kernel<<<dim3(64, 32), tb, 0, stream>>>(Wg, Wb, DD, HH);
  transcvt_kernel<<<dim3(64, 32), tb, 0, stream>>>(Wu, Wb + MH, DD, HH);
  transcvt_kernel<<<dim3(32, 64), tb, 0, stream>>>(Wd, Wb + 2 * MH, HH, DD);

  gateup_kernel<<<dim3(32, 64), 256, 0, stream>>>((const u16*)hb, Wb, Wb + MH,
                                                  actb, BT, HH, DD);
  mgemm_kernel<1><<<g1, 256, 0, stream>>>(actb, Wb + 2 * MH, x1, out,
                                          BT, DD, HH);
}